// Round 5
// baseline (280.890 us; speedup 1.0000x reference)
//
#include <hip/hip_runtime.h>
#include <hip/hip_bf16.h>

// Loss = L1*sl1(1,iou) + L2*sl1(t[:4],p[:4]) + L3*sl1(t[12],p[12]) + 0.5*L4*sl1(t[4:12],p[4:12])
// shapes: (B=256, N=8192, F=13) fp32. B*N = 2^21 rows.
//
// Single coalesced float4 streaming pass. Elementwise terms (loss2/3/4) are
// computed straight from registers with a mod-13 per-element weight. The IoU
// term's inputs (f0..3 of each row) are stashed into a compact LDS array
// DURING the stream (predicated ds_write, ~2.5 stores per 8 elements), so the
// IoU phase needs ZERO extra global reads — this removes R4's 90 MB re-fetch
// and its 26-cacheline scalar wave-loads. One barrier per block.
// 4096 blocks x 128 thr, 512 rows/block, 16 KB LDS -> 8 blocks/CU.

#define ROWS_TOTAL (256 * 8192)        // 2^21
#define TPB        128
#define RPB        512                 // rows per block
#define NBLK       (ROWS_TOTAL / RPB)  // 4096
#define F4PB       (RPB * 13 / 4)      // 1664 float4 per tensor per block

// Exact power-of-two mean weights (B*N = 2^21):
#define W1 (1.0f / 2097152.0f)    // loss1: 1/(B*N)
#define W2 (1.0f / 8388608.0f)    // loss2: 1/(B*N*4)
#define W3 (1.0f / 2097152.0f)    // loss3: 1/(B*N)
#define W4 (1.0f / 33554432.0f)   // loss4: 0.5/(B*N*8)

__device__ __forceinline__ float sl1(float d) {
    d = fabsf(d);
    return d < 1.0f ? 0.5f * d * d : d - 0.5f;
}

__global__ __launch_bounds__(TPB, 4) void loss_stage1(const float* __restrict__ T,
                                                      const float* __restrict__ P,
                                                      float* __restrict__ partial) {
    __shared__ float stT[RPB * 4];   // [row][f], f=0..3 box features of targets
    __shared__ float stP[RPB * 4];   // same for preds
    __shared__ float wred[2];

    const int tid = threadIdx.x;
    const int blk = blockIdx.x;

    const float4* t4 = (const float4*)T + (long long)blk * F4PB;
    const float4* p4 = (const float4*)P + (long long)blk * F4PB;

    const unsigned ftid = (4u * (unsigned)tid) % 13u;   // f of this thread's first element at k=0

    float acc = 0.0f;

    // ---- streaming pass: coalesced float4, weights + LDS box-stash ----
#pragma unroll
    for (int k = 0; k < 13; ++k) {
        const int i = k * TPB + tid;
        float4 a = t4[i];
        float4 b = p4[i];

        const unsigned e0   = 4u * (unsigned)i;          // block-local flat element idx
        unsigned       f0   = ftid + (unsigned)((512 * k) % 13);
        if (f0 >= 13u) f0 -= 13u;
        const unsigned row0 = e0 / 13u;                  // compiler emits magic-mul

        const float av[4] = {a.x, a.y, a.z, a.w};
        const float bv[4] = {b.x, b.y, b.z, b.w};
#pragma unroll
        for (int j = 0; j < 4; ++j) {
            unsigned f   = f0 + (unsigned)j;
            unsigned row = row0;
            if (f >= 13u) { f -= 13u; row += 1u; }
            float w = (f < 4u) ? W2 : ((f == 12u) ? W3 : W4);
            acc += w * sl1(av[j] - bv[j]);
            if (f < 4u) {                                // predicated stash of box features
                stT[row * 4u + f] = av[j];
                stP[row * 4u + f] = bv[j];
            }
        }
    }

    __syncthreads();   // the only barrier: stash complete

    // ---- IoU phase: 4 rows per thread, LDS b128 reads, no global traffic ----
#pragma unroll
    for (int k = 0; k < 4; ++k) {
        const int r = k * TPB + tid;
        float4 tb = ((const float4*)stT)[r];
        float4 pb = ((const float4*)stP)[r];

        float w = fmaxf(fminf(tb.z, pb.z) - fmaxf(tb.x, pb.x), 0.0f);
        float h = fmaxf(fminf(tb.w, pb.w) - fmaxf(tb.y, pb.y), 0.0f);
        float inter = w * h;
        float a1 = (tb.z - tb.x) * (tb.w - tb.y);
        float a2 = (pb.z - pb.x) * (pb.w - pb.y);
        float iou = inter / (a1 + a2 - inter + 1e-7f);
        acc += W1 * sl1(1.0f - iou);
    }

    // ---- block reduction: wave64 shuffle -> 2-wave LDS -> one partial ----
#pragma unroll
    for (int off = 32; off > 0; off >>= 1)
        acc += __shfl_down(acc, off, 64);
    if ((tid & 63) == 0) wred[tid >> 6] = acc;
    __syncthreads();
    if (tid == 0)
        partial[blk] = wred[0] + wred[1];
}

__global__ __launch_bounds__(256) void loss_stage2(const float* __restrict__ partial,
                                                   float* __restrict__ out) {
    __shared__ float wred[4];
    const int tid = threadIdx.x;
    float a = 0.0f;
#pragma unroll
    for (int k = 0; k < NBLK / 256; ++k) a += partial[k * 256 + tid];
#pragma unroll
    for (int off = 32; off > 0; off >>= 1)
        a += __shfl_down(a, off, 64);
    if ((tid & 63) == 0) wred[tid >> 6] = a;
    __syncthreads();
    if (tid == 0) out[0] = wred[0] + wred[1] + wred[2] + wred[3];
}

extern "C" void kernel_launch(void* const* d_in, const int* in_sizes, int n_in,
                              void* d_out, int out_size, void* d_ws, size_t ws_size,
                              hipStream_t stream) {
    const float* targets = (const float*)d_in[0];
    const float* preds   = (const float*)d_in[1];
    float* out     = (float*)d_out;
    float* partial = (float*)d_ws;   // NBLK floats = 16 KB scratch

    loss_stage1<<<NBLK, TPB, 0, stream>>>(targets, preds, partial);
    loss_stage2<<<1, 256, 0, stream>>>(partial, out);
}

// Round 6
// 234.391 us; speedup vs baseline: 1.1984x; 1.1984x over previous
//
#include <hip/hip_runtime.h>
#include <hip/hip_bf16.h>

// Loss = L1*sl1(1,iou) + L2*sl1(t[:4],p[:4]) + L3*sl1(t[12],p[12]) + 0.5*L4*sl1(t[4:12],p[4:12])
// shapes: (B=256, N=8192, F=13) fp32. B*N = 2^21 rows.
//
// R6: per-WAVE async pipeline. Each wave owns a private LDS double-buffer and
// a contiguous 1024-row stream; stages of 64 rows are fetched with width-4
// global_load_lds (no VGPR destinations -> nothing to spill) and retired with
// MANUAL s_waitcnt vmcnt(26) — no __syncthreads in the hot loop, so waves
// never drain their outstanding-load queue (R3's limiter). Consume reads are
// lane*13-strided scalar ds_read: 2-way bank aliasing only (free).
// 512 blocks x 256 thr; LDS 53,248 B/block. Partials (1/wave) -> stage2.

#define ROWS_TOTAL   (1 << 21)
#define TPB          256
#define WPB          4                         // waves per block
#define NBLK         512
#define NSTREAM      (NBLK * WPB)              // 2048 wave-streams
#define ROWS_STREAM  (ROWS_TOTAL / NSTREAM)    // 1024 rows per wave
#define ROWS_STAGE   64
#define NSTAGE       (ROWS_STREAM / ROWS_STAGE)  // 16
#define FLT_STAGE    (ROWS_STAGE * 13)         // 832 floats / tensor / stage

// s_waitcnt immediates (gfx9 encoding: vm[3:0]|[15:14], exp[6:4], lgkm[11:8])
#define WAIT_VM26    0x4F7A                    // vmcnt(26), exp/lgkm no-wait
#define WAIT_VM0     0x0F70                    // vmcnt(0),  exp/lgkm no-wait

// Exact power-of-two mean weights (B*N = 2^21):
#define W1 (1.0f / 2097152.0f)    // loss1: 1/(B*N)
#define W2 (1.0f / 8388608.0f)    // loss2: 1/(B*N*4)
#define W3 (1.0f / 2097152.0f)    // loss3: 1/(B*N)
#define W4 (1.0f / 33554432.0f)   // loss4: 0.5/(B*N*8)

typedef const __attribute__((address_space(1))) float gfloat;
typedef __attribute__((address_space(3))) float lfloat;

__device__ __forceinline__ float sl1(float d) {
    d = fabsf(d);
    return d < 1.0f ? 0.5f * d * d : d - 0.5f;
}

__global__ __launch_bounds__(TPB) void loss_stage1(const float* __restrict__ T,
                                                   const float* __restrict__ P,
                                                   float* __restrict__ partial) {
    // [wave][buf][tensor][floats] — per-wave private staging, no sharing.
    __shared__ float lds[WPB][2][2][FLT_STAGE];

    const int tid  = threadIdx.x;
    const int lane = tid & 63;
    const int wv   = tid >> 6;
    const int sid  = blockIdx.x * WPB + wv;                  // stream id
    const long long base13 = (long long)sid * ROWS_STREAM * 13;

    // Issue one stage (26 width-4 global_load_lds, 6656 B) into buffer b.
    auto issue = [&](int s, int b) {
        const float* tg = T + base13 + (long long)s * FLT_STAGE + lane;
        const float* pg = P + base13 + (long long)s * FLT_STAGE + lane;
        lfloat* lt = (lfloat*)&lds[wv][b][0][0];   // wave-uniform LDS base
        lfloat* lp = (lfloat*)&lds[wv][b][1][0];
#pragma unroll
        for (int i = 0; i < 13; ++i) {
            __builtin_amdgcn_global_load_lds((gfloat*)(tg + i * 64), lt + i * 64, 4, 0, 0);
            __builtin_amdgcn_global_load_lds((gfloat*)(pg + i * 64), lp + i * 64, 4, 0, 0);
        }
    };

    // Consume one stage: lane l processes row l (13 floats per tensor).
    float acc = 0.0f;
    auto consume = [&](int b) {
        const float* t = &lds[wv][b][0][lane * 13];
        const float* p = &lds[wv][b][1][lane * 13];

        float t0 = t[0], t1 = t[1], t2 = t[2], t3 = t[3];
        float p0 = p[0], p1 = p[1], p2 = p[2], p3 = p[3];

        float s2 = sl1(t0 - p0) + sl1(t1 - p1) + sl1(t2 - p2) + sl1(t3 - p3);

        float s4 = 0.0f;
#pragma unroll
        for (int f = 4; f < 12; ++f) s4 += sl1(t[f] - p[f]);

        float s3 = sl1(t[12] - p[12]);

        float w = fmaxf(fminf(t2, p2) - fmaxf(t0, p0), 0.0f);
        float h = fmaxf(fminf(t3, p3) - fmaxf(t1, p1), 0.0f);
        float inter = w * h;
        float a1 = (t2 - t0) * (t3 - t1);
        float a2 = (p2 - p0) * (p3 - p1);
        float iou = inter / (a1 + a2 - inter + 1e-7f);

        acc += W1 * sl1(1.0f - iou) + W2 * s2 + W3 * s3 + W4 * s4;
    };

    // ---- pipeline: prologue 2 stages ahead, then wait/consume/refill ----
    issue(0, 0);
    issue(1, 1);

#pragma unroll 1
    for (int s = 0; s < NSTAGE - 1; ++s) {
        __builtin_amdgcn_s_waitcnt(WAIT_VM26);   // oldest 26 retired => stage s in LDS
        asm volatile("" ::: "memory");           // pin ds_reads below the wait
        consume(s & 1);
        if (s < NSTAGE - 2) issue(s + 2, s & 1); // refill the freed buffer
    }
    __builtin_amdgcn_s_waitcnt(WAIT_VM0);        // last stage
    asm volatile("" ::: "memory");
    consume((NSTAGE - 1) & 1);

    // ---- wave reduction -> one partial per wave (no block barrier needed) ----
#pragma unroll
    for (int off = 32; off > 0; off >>= 1)
        acc += __shfl_down(acc, off, 64);
    if (lane == 0) partial[sid] = acc;
}

__global__ __launch_bounds__(256) void loss_stage2(const float* __restrict__ partial,
                                                   float* __restrict__ out) {
    __shared__ float wred[4];
    const int tid = threadIdx.x;
    float a = 0.0f;
#pragma unroll
    for (int k = 0; k < NSTREAM / 256; ++k) a += partial[k * 256 + tid];
#pragma unroll
    for (int off = 32; off > 0; off >>= 1)
        a += __shfl_down(a, off, 64);
    if ((tid & 63) == 0) wred[tid >> 6] = a;
    __syncthreads();
    if (tid == 0) out[0] = wred[0] + wred[1] + wred[2] + wred[3];
}

extern "C" void kernel_launch(void* const* d_in, const int* in_sizes, int n_in,
                              void* d_out, int out_size, void* d_ws, size_t ws_size,
                              hipStream_t stream) {
    const float* targets = (const float*)d_in[0];
    const float* preds   = (const float*)d_in[1];
    float* out     = (float*)d_out;
    float* partial = (float*)d_ws;   // NSTREAM floats = 8 KB scratch

    loss_stage1<<<NBLK, TPB, 0, stream>>>(targets, preds, partial);
    loss_stage2<<<1, 256, 0, stream>>>(partial, out);
}